// Round 8
// baseline (269.161 us; speedup 1.0000x reference)
//
#include <hip/hip_runtime.h>
#include <hip/hip_fp16.h>

#define GN 256
#define NPG 360
#define NN (GN*NPG)      // 92160
#define DEGAVG 16
#define EE (NN*DEGAVG)   // 1474560
#define EPG (NPG*DEGAVG) // 5760 edges per graph
#define HH 5
#define CC 30
#define IN_CH 11
#define NUM_GC 9
#define EPS 1e-5f

#define HLS 35   // h_l f32 row stride: 35%32=3 coprime -> conflict-free b32 patterns
#define H16S 18  // h16 row stride (u32 = 2 f16 ch): even -> 8B-aligned b64 reads
#define AGS 33   // agg row stride: (n+k)%32 distinct
#define SSS 5    // ssrc/sdst row stride
#define XS 12    // x row stride (floats): 16B-aligned rows

// ---- LDS layout (bytes) ----
#define OFF_HL     0        // float[360*35] = 50400
#define OFF_H16    50400    // uint [360*18] = 25920
#define OFF_EDGE   76320    // uint [5760]   = 23040
#define OFF_UNI    99360    // 47520: EGAT {x 17280 | ssrc 7200 | sdst 7200} / GC {agg 47520}
#define OFF_ROWP   146880   // u16  [364]    = 728
#define OFF_DEG    147608   // uint [360]    = 1440
#define OFF_POOL   149048   // float[300]    = 1200
#define OFF_FCH    150248   // float[56]     = 224
#define OFF_WA     150472   // float[112]    = 448
#define OFF_WSUM   150920   // uint [18]     = 72
#define SMEM_TOTAL 150992

__device__ __forceinline__ float f16_to_f32(unsigned short us) {
  __half_raw r; r.x = us; return __half2float(r);
}
__device__ __forceinline__ unsigned short f32_to_f16(float f) {
  __half h = __float2half(f);
  __half_raw r = *reinterpret_cast<__half_raw*>(&h);
  return r.x;
}

// ---------- InstanceNorm (f32 in place) + h16 repack + max pool: 15 ch-pairs x 32 lanes ----------
__device__ __forceinline__ void norm_pool(float* h_l, unsigned* h16_l, float* pooled_l,
                                          int layer, int tid) {
  int cp = tid >> 5, jj = tid & 31;
  if (cp < 15) {
    float va[12], vb[12];
    float sa = 0.f, s2a = 0.f, sb = 0.f, s2b = 0.f;
#pragma unroll
    for (int t = 0; t < 12; t++) {
      int i = jj + t * 32;
      float x = 0.f, y = 0.f;
      if (i < NPG) { x = h_l[i * HLS + 2 * cp]; y = h_l[i * HLS + 2 * cp + 1]; }
      va[t] = x; vb[t] = y;
      sa += x; s2a += x * x; sb += y; s2b += y * y;
    }
#pragma unroll
    for (int m = 16; m >= 1; m >>= 1) {
      sa += __shfl_xor(sa, m); s2a += __shfl_xor(s2a, m);
      sb += __shfl_xor(sb, m); s2b += __shfl_xor(s2b, m);
    }
    float ma = sa * (1.f / NPG), mb = sb * (1.f / NPG);
    float ra = rsqrtf(s2a * (1.f / NPG) - ma * ma + EPS);
    float rb = rsqrtf(s2b * (1.f / NPG) - mb * mb + EPS);
    float mxa = -1e30f, mxb = -1e30f;
#pragma unroll
    for (int t = 0; t < 12; t++) {
      int i = jj + t * 32;
      if (i < NPG) {
        float x = (va[t] - ma) * ra;
        float y = (vb[t] - mb) * rb;
        h_l[i * HLS + 2 * cp] = x;
        h_l[i * HLS + 2 * cp + 1] = y;
        h16_l[i * H16S + cp] = (unsigned)f32_to_f16(x) | ((unsigned)f32_to_f16(y) << 16);
        mxa = fmaxf(mxa, x); mxb = fmaxf(mxb, y);
      }
    }
#pragma unroll
    for (int m = 16; m >= 1; m >>= 1) {
      mxa = fmaxf(mxa, __shfl_xor(mxa, m));
      mxb = fmaxf(mxb, __shfl_xor(mxb, m));
    }
    if (jj == 0) {
      pooled_l[layer * CC + 2 * cp] = mxa;
      pooled_l[layer * CC + 2 * cp + 1] = mxb;
    }
  }
}

// ---------- GraphConv matmul half (compile-time channel base -> scalar weight loads) ----------
template <int CB>
__device__ __forceinline__ void mm_half(int n, const float* h_l, const float* agg_l,
                                        const float* Wr, const float* Wn, const float* bs,
                                        float* acc) {
#pragma unroll
  for (int c = 0; c < 15; c++) acc[c] = bs[CB + c];
  const float* hr = h_l + n * HLS;
  const float* ar = agg_l + n * AGS;
#pragma unroll
  for (int k = 0; k < CC; k++) {
    float hk = hr[k];
#pragma unroll
    for (int c = 0; c < 15; c++) acc[c] = fmaf(hk, Wr[k * CC + CB + c], acc[c]);
  }
#pragma unroll
  for (int k = 0; k < CC; k++) {
    float ak = ar[k];
#pragma unroll
    for (int c = 0; c < 15; c++) acc[c] = fmaf(ak, Wn[k * CC + CB + c], acc[c]);
  }
}

// ---------- mega-kernel ----------
__global__ __launch_bounds__(1024, 4) void k_mega(
    const float* __restrict__ x, const int* __restrict__ ei, const float* __restrict__ eattr,
    const float* __restrict__ egw, const float* __restrict__ att_s,
    const float* __restrict__ att_d, const float* __restrict__ att_e,
    const float* __restrict__ wroot, const float* __restrict__ wnbr,
    const float* __restrict__ gcb,
    const float* __restrict__ fc1w, const float* __restrict__ fc1b,
    const float* __restrict__ fc2w, const float* __restrict__ fc2b,
    float* __restrict__ out) {
  __shared__ __align__(16) unsigned char smem[SMEM_TOTAL];
  float*          h_l     = (float*)(smem + OFF_HL);
  unsigned*       h16_l   = (unsigned*)(smem + OFF_H16);
  unsigned*       edge_l  = (unsigned*)(smem + OFF_EDGE);
  float*          x_l     = (float*)(smem + OFF_UNI);
  float*          ssrc_l  = (float*)(smem + OFF_UNI) + NPG * XS;
  float*          sdst_l  = (float*)(smem + OFF_UNI) + NPG * XS + NPG * SSS;
  float*          agg_l   = (float*)(smem + OFF_UNI);          // GC-phase alias
  unsigned short* rowp_l  = (unsigned short*)(smem + OFF_ROWP);
  unsigned*       deg_l   = (unsigned*)(smem + OFF_DEG);
  float*          pooled_l= (float*)(smem + OFF_POOL);
  float*          fch     = (float*)(smem + OFF_FCH);
  float*          wa_l    = (float*)(smem + OFF_WA);
  unsigned*       wsum    = (unsigned*)(smem + OFF_WSUM);

  const int g = blockIdx.x, tid = threadIdx.x;
  const int nb = g * NPG;
  const int ebase = g * EPG;            // edges are graph-contiguous by construction
  const int lane = tid & 63, wid = tid >> 6;

  // ---- P0: zero deg + h16, stage x (f32, padded rows of 12) ----
  for (int i = tid; i < NPG; i += 1024) deg_l[i] = 0u;
  for (int i = tid; i < NPG * H16S; i += 1024) h16_l[i] = 0u;
  for (int it = tid; it < NPG * XS; it += 1024) {
    int n = it / XS, i = it - n * XS;
    x_l[it] = (i < IN_CH) ? x[(size_t)(nb + n) * IN_CH + i] : 0.f;
  }
  __syncthreads();

  // ---- P1: degree histogram (LDS atomics) + wa precontraction ----
  for (int e = tid; e < EPG; e += 1024) {
    int d = ei[EE + ebase + e] - nb;
    atomicAdd(&deg_l[d], 1u);
  }
  if (tid < 110) {
    int half = tid >= 55;
    int idx = tid - half * 55;
    int i = idx / 5, h = idx - i * 5;
    const float* av = half ? att_d : att_s;
    float s = 0.f;
#pragma unroll
    for (int c = 0; c < CC; c++) s += egw[(i * HH + h) * CC + c] * av[h * CC + c];
    wa_l[tid] = s;
  }
  __syncthreads();

  // ---- P2: block scan of degrees -> rowp_l ----
  {
    unsigned v = (tid < NPG) ? deg_l[tid] : 0u;
#pragma unroll
    for (int off = 1; off < 64; off <<= 1) {
      unsigned t = (unsigned)__shfl_up((int)v, off);
      if (lane >= off) v += t;
    }
    if (lane == 63) wsum[wid] = v;
    __syncthreads();
    if (tid == 0) {
      unsigned run = 0;
      for (int i = 0; i < 16; i++) { unsigned t = wsum[i]; wsum[i] = run; run += t; }
    }
    __syncthreads();
    if (tid < NPG) rowp_l[tid + 1] = (unsigned short)(v + wsum[wid]);
    if (tid == 0) rowp_l[0] = 0;
    if (tid < NPG) deg_l[tid] = 0u;     // becomes scatter cursor
  }
  __syncthreads();

  // ---- P3: scatter edges into CSR (raw src | eattr_f16) + ssrc/sdst dots ----
  for (int e = tid; e < EPG; e += 1024) {
    int s = ei[ebase + e] - nb;
    int d = ei[EE + ebase + e] - nb;
    float ea = eattr[ebase + e];
    unsigned pos = (unsigned)rowp_l[d] + atomicAdd(&deg_l[d], 1u);
    edge_l[pos] = (unsigned)s | ((unsigned)f32_to_f16(ea) << 16);
  }
  if (tid < NPG) {
    float xi[IN_CH];
#pragma unroll
    for (int i = 0; i < IN_CH; i++) xi[i] = x_l[tid * XS + i];
#pragma unroll
    for (int h = 0; h < HH; h++) {
      float s1 = 0.f, s2 = 0.f;
#pragma unroll
      for (int i = 0; i < IN_CH; i++) {
        s1 = fmaf(xi[i], wa_l[i * HH + h], s1);
        s2 = fmaf(xi[i], wa_l[55 + i * HH + h], s2);
      }
      ssrc_l[tid * SSS + h] = s1;
      sdst_l[tid * SSS + h] = s2;
    }
  }
  __syncthreads();

  // ---- P4: EGAT thread-per-node, 2 passes (max-shift cancels; |logit| small) ----
  if (tid < NPG) {
    const int n = tid;
    const int b = rowp_l[n], en = rowp_l[n + 1];
    float sd[HH], ae[HH];
#pragma unroll
    for (int h = 0; h < HH; h++) { sd[h] = sdst_l[n * SSS + h]; ae[h] = att_e[h]; }
    float dn[HH];
#pragma unroll
    for (int h = 0; h < HH; h++) dn[h] = 0.f;
    for (int p = b; p < en; p++) {            // pass 1: denominators
      unsigned u = edge_l[p];
      int s = u & 0xffffu;
      float ea = f16_to_f32((unsigned short)(u >> 16));
      const float* sr = ssrc_l + s * SSS;
#pragma unroll
      for (int h = 0; h < HH; h++) {
        float lg = sr[h] + sd[h] + ea * ae[h];
        lg = lg > 0.f ? lg : 0.2f * lg;
        dn[h] += __expf(lg);
      }
    }
    float rdn[HH];
#pragma unroll
    for (int h = 0; h < HH; h++) rdn[h] = 1.f / (dn[h] + 1e-16f);
    float gg[55];
#pragma unroll
    for (int k = 0; k < 55; k++) gg[k] = 0.f;
    for (int p = b; p < en; p++) {            // pass 2: alpha, 11-dim gather, edge rewrite
      unsigned u = edge_l[p];
      int s = u & 0xffffu;
      float ea = f16_to_f32((unsigned short)(u >> 16));
      const float* sr = ssrc_l + s * SSS;
      const float* xr = x_l + s * XS;
      const float4 xv0 = *(const float4*)(xr);
      const float4 xv1 = *(const float4*)(xr + 4);
      const float4 xv2 = *(const float4*)(xr + 8);
      const float xi[IN_CH] = {xv0.x, xv0.y, xv0.z, xv0.w, xv1.x, xv1.y, xv1.z, xv1.w,
                               xv2.x, xv2.y, xv2.z};
      float ews = 0.f;
#pragma unroll
      for (int h = 0; h < HH; h++) {
        float lg = sr[h] + sd[h] + ea * ae[h];
        lg = lg > 0.f ? lg : 0.2f * lg;
        float a = __expf(lg) * rdn[h];
        ews += a;
#pragma unroll
        for (int i = 0; i < IN_CH; i++) gg[h * IN_CH + i] = fmaf(a, xi[i], gg[h * IN_CH + i]);
      }
      // rewrite edge: premultiplied h16 u32-offset | f16(mean-head alpha)
      edge_l[p] = (unsigned)(s * H16S) | ((unsigned)f32_to_f16(ews * 0.2f) << 16);
    }
    // h = 0.2 * sum_h g_h . W_h  (uniform scalar weight loads)
#pragma unroll
    for (int half = 0; half < 2; half++) {
      float acc[15];
#pragma unroll
      for (int c = 0; c < 15; c++) acc[c] = 0.f;
#pragma unroll
      for (int i = 0; i < IN_CH; i++) {
#pragma unroll
        for (int h = 0; h < HH; h++) {
          float gv = gg[h * IN_CH + i];
          const float* wr = egw + (i * HH + h) * CC + half * 15;
#pragma unroll
          for (int c = 0; c < 15; c++) acc[c] = fmaf(gv, wr[c], acc[c]);
        }
      }
#pragma unroll
      for (int c = 0; c < 15; c++) h_l[n * HLS + half * 15 + c] = 0.2f * acc[c];
    }
  }
  __syncthreads();

  // ---- P5: norm0 + h16 repack + pooled[0] ----
  norm_pool(h_l, h16_l, pooled_l, 0, tid);
  __syncthreads();

  // ---- GC stack ----
  const int es = lane >> 3;          // edge slot 0..7
  const int q  = lane & 7;           // channel quad: ch 4q..4q+3
#pragma unroll 1
  for (int l = 0; l < NUM_GC; l++) {
    // gather: wave per node, 8 edges x 8 lanes x b64 (4 f16 ch); 2-deep unrolled
    for (int n = wid; n < NPG; n += 16) {
      int b = rowp_l[n], en = rowp_l[n + 1];
      float a0 = 0.f, a1 = 0.f, a2 = 0.f, a3 = 0.f;
      int p = b + es;
      for (; p + 8 < en; p += 16) {
        unsigned ua = edge_l[p];
        unsigned ub = edge_l[p + 8];
        uint2 hva = *(const uint2*)(h16_l + (ua & 0xffffu) + 2 * q);
        uint2 hvb = *(const uint2*)(h16_l + (ub & 0xffffu) + 2 * q);
        float wa = f16_to_f32((unsigned short)(ua >> 16));
        float wb = f16_to_f32((unsigned short)(ub >> 16));
        float2 fa0 = __half22float2(*(const __half2*)&hva.x);
        float2 fa1 = __half22float2(*(const __half2*)&hva.y);
        float2 fb0 = __half22float2(*(const __half2*)&hvb.x);
        float2 fb1 = __half22float2(*(const __half2*)&hvb.y);
        a0 = fmaf(wa, fa0.x, a0); a1 = fmaf(wa, fa0.y, a1);
        a2 = fmaf(wa, fa1.x, a2); a3 = fmaf(wa, fa1.y, a3);
        a0 = fmaf(wb, fb0.x, a0); a1 = fmaf(wb, fb0.y, a1);
        a2 = fmaf(wb, fb1.x, a2); a3 = fmaf(wb, fb1.y, a3);
      }
      if (p < en) {
        unsigned u = edge_l[p];
        float w = f16_to_f32((unsigned short)(u >> 16));
        uint2 hv = *(const uint2*)(h16_l + (u & 0xffffu) + 2 * q);
        float2 f0 = __half22float2(*(const __half2*)&hv.x);
        float2 f1 = __half22float2(*(const __half2*)&hv.y);
        a0 = fmaf(w, f0.x, a0); a1 = fmaf(w, f0.y, a1);
        a2 = fmaf(w, f1.x, a2); a3 = fmaf(w, f1.y, a3);
      }
#pragma unroll
      for (int m = 8; m <= 32; m <<= 1) {
        a0 += __shfl_xor(a0, m); a1 += __shfl_xor(a1, m);
        a2 += __shfl_xor(a2, m); a3 += __shfl_xor(a3, m);
      }
      if (es == 0) {
        float* ar = agg_l + n * AGS + 4 * q;
        ar[0] = a0; ar[1] = a1; ar[2] = a2; ar[3] = a3;
      }
    }
    __syncthreads();
    // matmul halves: compute (reads) -> barrier -> write (avoids cross-half RW race)
    const float* Wr = wroot + l * CC * CC;
    const float* Wn = wnbr + l * CC * CC;
    const float* bs = gcb + l * CC;
    float acc[15];
    int n = -1, cb = 0;
    if (tid < NPG) { n = tid; cb = 0; mm_half<0>(n, h_l, agg_l, Wr, Wn, bs, acc); }
    else if (tid >= 512 && tid < 512 + NPG) { n = tid - 512; cb = 15; mm_half<15>(n, h_l, agg_l, Wr, Wn, bs, acc); }
    __syncthreads();
    if (n >= 0) {
#pragma unroll
      for (int c = 0; c < 15; c++) h_l[n * HLS + cb + c] = acc[c];
    }
    __syncthreads();
    norm_pool(h_l, h16_l, pooled_l, l + 1, tid);
    __syncthreads();
  }

  // ---- final MLP ----
  if (tid < 50) {
    float a = fc1b[tid];
    for (int i = 0; i < 10 * CC; i++) a = fmaf(pooled_l[i], fc1w[i * 50 + tid], a);
    fch[tid] = fmaxf(a, 0.f);
  }
  __syncthreads();
  if (tid < 2) {
    float o = fc2b[tid];
#pragma unroll
    for (int j = 0; j < 50; j++) o = fmaf(fch[j], fc2w[j * 2 + tid], o);
    out[g * 2 + tid] = o;
  }
}

extern "C" void kernel_launch(void* const* d_in, const int* in_sizes, int n_in,
                              void* d_out, int out_size, void* d_ws, size_t ws_size,
                              hipStream_t stream) {
  (void)d_ws; (void)ws_size; (void)in_sizes; (void)n_in; (void)out_size;
  const float* x     = (const float*)d_in[0];
  const int*   ei    = (const int*)d_in[1];
  const float* eattr = (const float*)d_in[2];
  const float* egw   = (const float*)d_in[4];
  const float* att_s = (const float*)d_in[5];
  const float* att_d = (const float*)d_in[6];
  const float* att_e = (const float*)d_in[7];
  const float* wroot = (const float*)d_in[8];
  const float* wnbr  = (const float*)d_in[9];
  const float* gcb   = (const float*)d_in[10];
  const float* fc1w  = (const float*)d_in[11];
  const float* fc1b  = (const float*)d_in[12];
  const float* fc2w  = (const float*)d_in[13];
  const float* fc2b  = (const float*)d_in[14];
  float* out = (float*)d_out;

  k_mega<<<GN, 1024, 0, stream>>>(x, ei, eattr, egw, att_s, att_d, att_e,
                                  wroot, wnbr, gcb, fc1w, fc1b, fc2w, fc2b, out);
}

// Round 9
// 262.027 us; speedup vs baseline: 1.0272x; 1.0272x over previous
//
#include <hip/hip_runtime.h>
#include <hip/hip_fp16.h>

#define GN 256
#define NPG 360
#define NN (GN*NPG)      // 92160
#define DEGAVG 16
#define EE (NN*DEGAVG)   // 1474560
#define EPG (NPG*DEGAVG) // 5760 edges per graph
#define HH 5
#define CC 30
#define IN_CH 11
#define NUM_GC 9
#define EPS 1e-5f

#define HLS 35   // h_l f32 row stride: 35%32=3 coprime -> conflict-free b32 patterns
#define AGS 33   // agg row stride: (n+k)%32 distinct
#define SSS 5    // ssrc/sdst row stride
#define XS 12    // x row stride (floats): 16B-aligned rows

// ---- LDS layout (bytes) ----
#define OFF_HL     0        // float[360*35] = 50400
#define OFF_EDGE   50400    // uint [5760]   = 23040
#define OFF_UNI    73440    // 47520: EGAT {x 17280 | ssrc 7200 | sdst 7200} / GC {agg 47520}
#define OFF_ROWP   120960   // u16  [364]    = 728
#define OFF_DEG    121688   // uint [360]    = 1440
#define OFF_POOL   123128   // float[300]    = 1200
#define OFF_FCH    124328   // float[56]     = 224
#define OFF_WA     124552   // float[112]    = 448
#define OFF_WSUM   125000   // uint [18]     = 72
#define SMEM_TOTAL 125072

__device__ __forceinline__ float f16_to_f32(unsigned short us) {
  __half_raw r; r.x = us; return __half2float(r);
}
__device__ __forceinline__ unsigned short f32_to_f16(float f) {
  __half h = __float2half(f);
  __half_raw r = *reinterpret_cast<__half_raw*>(&h);
  return r.x;
}

// ---------- InstanceNorm (in place, f32) + per-graph max pool: 30 ch x 32 lanes ----------
__device__ __forceinline__ void norm_pool(float* h_l, float* pooled_l, int layer, int tid) {
  int c = tid >> 5, jj = tid & 31;
  if (c < CC) {
    float va[12];
    float s = 0.f, s2 = 0.f;
#pragma unroll
    for (int t = 0; t < 12; t++) {
      int i = jj + t * 32;
      float v = (i < NPG) ? h_l[i * HLS + c] : 0.f;
      va[t] = v; s += v; s2 += v * v;
    }
#pragma unroll
    for (int m = 16; m >= 1; m >>= 1) { s += __shfl_xor(s, m); s2 += __shfl_xor(s2, m); }
    float mean = s * (1.f / NPG);
    float rs = rsqrtf(s2 * (1.f / NPG) - mean * mean + EPS);
    float mx = -1e30f;
#pragma unroll
    for (int t = 0; t < 12; t++) {
      int i = jj + t * 32;
      if (i < NPG) {
        float v = (va[t] - mean) * rs;
        h_l[i * HLS + c] = v;
        mx = fmaxf(mx, v);
      }
    }
#pragma unroll
    for (int m = 16; m >= 1; m >>= 1) mx = fmaxf(mx, __shfl_xor(mx, m));
    if (jj == 0) pooled_l[layer * CC + c] = mx;
  }
}

// ---------- GraphConv matmul half (compile-time channel base -> scalar weight loads) ----------
template <int CB>
__device__ __forceinline__ void mm_half(int n, const float* h_l, const float* agg_l,
                                        const float* Wr, const float* Wn, const float* bs,
                                        float* acc) {
#pragma unroll
  for (int c = 0; c < 15; c++) acc[c] = bs[CB + c];
  const float* hr = h_l + n * HLS;
  const float* ar = agg_l + n * AGS;
#pragma unroll
  for (int k = 0; k < CC; k++) {
    float hk = hr[k];
#pragma unroll
    for (int c = 0; c < 15; c++) acc[c] = fmaf(hk, Wr[k * CC + CB + c], acc[c]);
  }
#pragma unroll
  for (int k = 0; k < CC; k++) {
    float ak = ar[k];
#pragma unroll
    for (int c = 0; c < 15; c++) acc[c] = fmaf(ak, Wn[k * CC + CB + c], acc[c]);
  }
}

// ---------- mega-kernel ----------
__global__ __launch_bounds__(1024, 4) void k_mega(
    const float* __restrict__ x, const int* __restrict__ ei, const float* __restrict__ eattr,
    const float* __restrict__ egw, const float* __restrict__ att_s,
    const float* __restrict__ att_d, const float* __restrict__ att_e,
    const float* __restrict__ wroot, const float* __restrict__ wnbr,
    const float* __restrict__ gcb,
    const float* __restrict__ fc1w, const float* __restrict__ fc1b,
    const float* __restrict__ fc2w, const float* __restrict__ fc2b,
    float* __restrict__ out) {
  __shared__ __align__(16) unsigned char smem[SMEM_TOTAL];
  float*          h_l     = (float*)(smem + OFF_HL);
  unsigned*       edge_l  = (unsigned*)(smem + OFF_EDGE);
  float*          x_l     = (float*)(smem + OFF_UNI);
  float*          ssrc_l  = (float*)(smem + OFF_UNI) + NPG * XS;
  float*          sdst_l  = (float*)(smem + OFF_UNI) + NPG * XS + NPG * SSS;
  float*          agg_l   = (float*)(smem + OFF_UNI);          // GC-phase alias
  unsigned short* rowp_l  = (unsigned short*)(smem + OFF_ROWP);
  unsigned*       deg_l   = (unsigned*)(smem + OFF_DEG);
  float*          pooled_l= (float*)(smem + OFF_POOL);
  float*          fch     = (float*)(smem + OFF_FCH);
  float*          wa_l    = (float*)(smem + OFF_WA);
  unsigned*       wsum    = (unsigned*)(smem + OFF_WSUM);

  const int g = blockIdx.x, tid = threadIdx.x;
  const int nb = g * NPG;
  const int ebase = g * EPG;            // edges are graph-contiguous by construction
  const int lane = tid & 63, wid = tid >> 6;

  // ---- P0: zero deg, stage x (f32, padded rows of 12) ----
  for (int i = tid; i < NPG; i += 1024) deg_l[i] = 0u;
  for (int it = tid; it < NPG * XS; it += 1024) {
    int n = it / XS, i = it - n * XS;
    x_l[it] = (i < IN_CH) ? x[(size_t)(nb + n) * IN_CH + i] : 0.f;
  }
  __syncthreads();

  // ---- P1: degree histogram (LDS atomics) + wa precontraction ----
  for (int e = tid; e < EPG; e += 1024) {
    int d = ei[EE + ebase + e] - nb;
    atomicAdd(&deg_l[d], 1u);
  }
  if (tid < 110) {
    int half = tid >= 55;
    int idx = tid - half * 55;
    int i = idx / 5, h = idx - i * 5;
    const float* av = half ? att_d : att_s;
    float s = 0.f;
#pragma unroll
    for (int c = 0; c < CC; c++) s += egw[(i * HH + h) * CC + c] * av[h * CC + c];
    wa_l[tid] = s;
  }
  __syncthreads();

  // ---- P2: block scan of degrees -> rowp_l ----
  {
    unsigned v = (tid < NPG) ? deg_l[tid] : 0u;
#pragma unroll
    for (int off = 1; off < 64; off <<= 1) {
      unsigned t = (unsigned)__shfl_up((int)v, off);
      if (lane >= off) v += t;
    }
    if (lane == 63) wsum[wid] = v;
    __syncthreads();
    if (tid == 0) {
      unsigned run = 0;
      for (int i = 0; i < 16; i++) { unsigned t = wsum[i]; wsum[i] = run; run += t; }
    }
    __syncthreads();
    if (tid < NPG) rowp_l[tid + 1] = (unsigned short)(v + wsum[wid]);
    if (tid == 0) rowp_l[0] = 0;
    if (tid < NPG) deg_l[tid] = 0u;     // becomes scatter cursor
  }
  __syncthreads();

  // ---- P3: scatter edges into CSR (raw src | eattr_f16) + ssrc/sdst dots ----
  for (int e = tid; e < EPG; e += 1024) {
    int s = ei[ebase + e] - nb;
    int d = ei[EE + ebase + e] - nb;
    float ea = eattr[ebase + e];
    unsigned pos = (unsigned)rowp_l[d] + atomicAdd(&deg_l[d], 1u);
    edge_l[pos] = (unsigned)s | ((unsigned)f32_to_f16(ea) << 16);
  }
  if (tid < NPG) {
    float xi[IN_CH];
#pragma unroll
    for (int i = 0; i < IN_CH; i++) xi[i] = x_l[tid * XS + i];
#pragma unroll
    for (int h = 0; h < HH; h++) {
      float s1 = 0.f, s2 = 0.f;
#pragma unroll
      for (int i = 0; i < IN_CH; i++) {
        s1 = fmaf(xi[i], wa_l[i * HH + h], s1);
        s2 = fmaf(xi[i], wa_l[55 + i * HH + h], s2);
      }
      ssrc_l[tid * SSS + h] = s1;
      sdst_l[tid * SSS + h] = s2;
    }
  }
  __syncthreads();

  // ---- P4: EGAT, thread-PAIR per node: slot handles alternate edges ----
  if (tid < 2 * NPG) {
    const int n = tid >> 1, slot = tid & 1;
    const int b = rowp_l[n], en = rowp_l[n + 1];
    float sd[HH], ae[HH];
#pragma unroll
    for (int h = 0; h < HH; h++) { sd[h] = sdst_l[n * SSS + h]; ae[h] = att_e[h]; }
    float dn[HH];
#pragma unroll
    for (int h = 0; h < HH; h++) dn[h] = 0.f;
    for (int p = b + slot; p < en; p += 2) {      // pass 1: partial denominators
      unsigned u = edge_l[p];
      int s = u & 0xffffu;
      float ea = f16_to_f32((unsigned short)(u >> 16));
      const float* sr = ssrc_l + s * SSS;
#pragma unroll
      for (int h = 0; h < HH; h++) {
        float lg = sr[h] + sd[h] + ea * ae[h];
        lg = lg > 0.f ? lg : 0.2f * lg;
        dn[h] += __expf(lg);
      }
    }
    float rdn[HH];
#pragma unroll
    for (int h = 0; h < HH; h++) {
      dn[h] += __shfl_xor(dn[h], 1);              // pair combine
      rdn[h] = 1.f / (dn[h] + 1e-16f);
    }
    float gg[55];
#pragma unroll
    for (int k = 0; k < 55; k++) gg[k] = 0.f;
    for (int p = b + slot; p < en; p += 2) {      // pass 2: alpha, gather, edge rewrite
      unsigned u = edge_l[p];
      int s = u & 0xffffu;
      float ea = f16_to_f32((unsigned short)(u >> 16));
      const float* sr = ssrc_l + s * SSS;
      const float* xr = x_l + s * XS;
      const float4 xv0 = *(const float4*)(xr);
      const float4 xv1 = *(const float4*)(xr + 4);
      const float4 xv2 = *(const float4*)(xr + 8);
      const float xi[IN_CH] = {xv0.x, xv0.y, xv0.z, xv0.w, xv1.x, xv1.y, xv1.z, xv1.w,
                               xv2.x, xv2.y, xv2.z};
      float ews = 0.f;
#pragma unroll
      for (int h = 0; h < HH; h++) {
        float lg = sr[h] + sd[h] + ea * ae[h];
        lg = lg > 0.f ? lg : 0.2f * lg;
        float a = __expf(lg) * rdn[h];
        ews += a;
#pragma unroll
        for (int i = 0; i < IN_CH; i++) gg[h * IN_CH + i] = fmaf(a, xi[i], gg[h * IN_CH + i]);
      }
      // rewrite edge: premultiplied h_l float offset | f16(mean-head alpha)
      edge_l[p] = (unsigned)(s * HLS) | ((unsigned)f32_to_f16(ews * 0.2f) << 16);
    }
#pragma unroll
    for (int k = 0; k < 55; k++) gg[k] += __shfl_xor(gg[k], 1);   // pair combine
    // contract (slot 0 only -> wave-uniform scalar weight loads):
    // h = 0.2 * sum_h g_h . W_h
    if (slot == 0) {
#pragma unroll
      for (int half = 0; half < 2; half++) {
        float acc[15];
#pragma unroll
        for (int c = 0; c < 15; c++) acc[c] = 0.f;
#pragma unroll
        for (int i = 0; i < IN_CH; i++) {
#pragma unroll
          for (int h = 0; h < HH; h++) {
            float gv = gg[h * IN_CH + i];
            const float* wr = egw + (i * HH + h) * CC + half * 15;
#pragma unroll
            for (int c = 0; c < 15; c++) acc[c] = fmaf(gv, wr[c], acc[c]);
          }
        }
#pragma unroll
        for (int c = 0; c < 15; c++) h_l[n * HLS + half * 15 + c] = 0.2f * acc[c];
      }
    }
  }
  __syncthreads();

  // ---- P5: norm0 + pooled[0] ----
  norm_pool(h_l, pooled_l, 0, tid);
  __syncthreads();

  // ---- GC stack ----
  const int es = lane >> 5;          // edge slot 0/1
  const int cg = lane & 31;          // channel (30,31 dummy)
#pragma unroll 1
  for (int l = 0; l < NUM_GC; l++) {
    // gather: wave per node, 2 edges x 32 channels, software-pipelined 1 deep;
    // banks (3s+c)%32 fully spread -> 2-way (free)
    for (int n = wid; n < NPG; n += 16) {
      int b = rowp_l[n], en = rowp_l[n + 1];
      float a = 0.f;
      int p = b + es;
      if (p < en) {
        unsigned u = edge_l[p];
        float hv = h_l[(u & 0xffffu) + cg];
        for (p += 2; p < en; p += 2) {
          unsigned u2 = edge_l[p];                 // prefetch next edge word
          float hv2 = h_l[(u2 & 0xffffu) + cg];    // prefetch next h value
          a = fmaf(f16_to_f32((unsigned short)(u >> 16)), hv, a);
          u = u2; hv = hv2;
        }
        a = fmaf(f16_to_f32((unsigned short)(u >> 16)), hv, a);
      }
      a += __shfl_xor(a, 32);
      if (lane < CC) agg_l[n * AGS + lane] = a;
    }
    __syncthreads();
    // matmul halves: compute (reads) -> barrier -> write (avoids cross-half RW race)
    const float* Wr = wroot + l * CC * CC;
    const float* Wn = wnbr + l * CC * CC;
    const float* bs = gcb + l * CC;
    float acc[15];
    int n = -1, cb = 0;
    if (tid < NPG) { n = tid; cb = 0; mm_half<0>(n, h_l, agg_l, Wr, Wn, bs, acc); }
    else if (tid >= 512 && tid < 512 + NPG) { n = tid - 512; cb = 15; mm_half<15>(n, h_l, agg_l, Wr, Wn, bs, acc); }
    __syncthreads();
    if (n >= 0) {
#pragma unroll
      for (int c = 0; c < 15; c++) h_l[n * HLS + cb + c] = acc[c];
    }
    __syncthreads();
    norm_pool(h_l, pooled_l, l + 1, tid);
    __syncthreads();
  }

  // ---- final MLP ----
  if (tid < 50) {
    float a = fc1b[tid];
    for (int i = 0; i < 10 * CC; i++) a = fmaf(pooled_l[i], fc1w[i * 50 + tid], a);
    fch[tid] = fmaxf(a, 0.f);
  }
  __syncthreads();
  if (tid < 2) {
    float o = fc2b[tid];
#pragma unroll
    for (int j = 0; j < 50; j++) o = fmaf(fch[j], fc2w[j * 2 + tid], o);
    out[g * 2 + tid] = o;
  }
}

extern "C" void kernel_launch(void* const* d_in, const int* in_sizes, int n_in,
                              void* d_out, int out_size, void* d_ws, size_t ws_size,
                              hipStream_t stream) {
  (void)d_ws; (void)ws_size; (void)in_sizes; (void)n_in; (void)out_size;
  const float* x     = (const float*)d_in[0];
  const int*   ei    = (const int*)d_in[1];
  const float* eattr = (const float*)d_in[2];
  const float* egw   = (const float*)d_in[4];
  const float* att_s = (const float*)d_in[5];
  const float* att_d = (const float*)d_in[6];
  const float* att_e = (const float*)d_in[7];
  const float* wroot = (const float*)d_in[8];
  const float* wnbr  = (const float*)d_in[9];
  const float* gcb   = (const float*)d_in[10];
  const float* fc1w  = (const float*)d_in[11];
  const float* fc1b  = (const float*)d_in[12];
  const float* fc2w  = (const float*)d_in[13];
  const float* fc2b  = (const float*)d_in[14];
  float* out = (float*)d_out;

  k_mega<<<GN, 1024, 0, stream>>>(x, ei, eattr, egw, att_s, att_d, att_e,
                                  wroot, wnbr, gcb, fc1w, fc1b, fc2w, fc2b, out);
}